// Round 9
// baseline (271.460 us; speedup 1.0000x reference)
//
#include <hip/hip_runtime.h>
#include <hip/hip_cooperative_groups.h>
namespace cg = cooperative_groups;

#define B_ 4096
#define C_ 128
#define D_ 768
#define NBLK 256
#define NT 512
#define NW (NT/64)
#define M_CAP 96
#define P_CAP (M_CAP*(M_CAP-1)/2)   // 4560
#define NB_H 1024
#define SG_CAP 131072

__device__ __forceinline__ float wave_red(float v){
#pragma unroll
  for (int o = 32; o > 0; o >>= 1) v += __shfl_down(v, o, 64);
  return v;
}
__device__ __forceinline__ float wave_min(float v){
#pragma unroll
  for (int o = 32; o > 0; o >>= 1) v = fminf(v, __shfl_down(v, o, 64));
  return v;
}
__device__ __forceinline__ float wave_max(float v){
#pragma unroll
  for (int o = 32; o > 0; o >>= 1) v = fmaxf(v, __shfl_down(v, o, 64));
  return v;
}
__device__ __forceinline__ float clamp1(float x){ return fminf(fmaxf(x, -1.f), 1.f); }
__device__ __forceinline__ unsigned rotl32(unsigned x, int r){ return (x << r) | (x >> (32 - r)); }
__device__ __forceinline__ float dot4(float4 a, float4 b){
  return fmaf(a.x, b.x, fmaf(a.y, b.y, fmaf(a.z, b.z, a.w * b.w)));
}

// jax.random.uniform(jax.random.key(1),(B,B)) element n: Threefry-2x32 key (0,1),
// counters split in halves. Bit-exact (verified rounds 1-8: absmax 0.0).
__device__ float rand_ij(unsigned n){
  const unsigned half = (unsigned)B_ * (unsigned)B_ / 2u;
  unsigned c0, c1; bool hi;
  if (n < half){ c0 = n; c1 = n + half; hi = false; }
  else         { c0 = n - half; c1 = n; hi = true; }
  const unsigned K0 = 0u, K1 = 1u, K2 = 0x1BD11BDBu;
  unsigned x0 = c0 + K0, x1 = c1 + K1;
#define TFR(r) { x0 += x1; x1 = rotl32(x1, (r)); x1 ^= x0; }
  TFR(13) TFR(15) TFR(26) TFR(6)  x0 += K1; x1 += K2 + 1u;
  TFR(17) TFR(29) TFR(16) TFR(24) x0 += K2; x1 += K0 + 2u;
  TFR(13) TFR(15) TFR(26) TFR(6)  x0 += K0; x1 += K1 + 3u;
  TFR(17) TFR(29) TFR(16) TFR(24) x0 += K1; x1 += K2 + 4u;
  TFR(13) TFR(15) TFR(26) TFR(6)  x0 += K2; x1 += K0 + 5u;
#undef TFR
  unsigned bits = hi ? x1 : x0;
  return __uint_as_float((bits >> 9) | 0x3F800000u) - 1.0f;
}

// p -> (a,b), a<b<m, row-major upper-tri. before(a) = a*(2m-1-a)/2.
__device__ __forceinline__ void decode_pair(int p, int m, int* a_, int* b_){
  float fm = (float)(2*m - 1);
  int a = (int)((fm - sqrtf(fm*fm - 8.0f*(float)p)) * 0.5f);
  a = max(0, min(a, m - 2));
  while (a > 0 && (a*(2*m - 1 - a))/2 > p) --a;
  while (((a + 1)*(2*m - 2 - a))/2 <= p) ++a;
  *a_ = a;
  *b_ = a + 1 + (p - (a*(2*m - 1 - a))/2);
}

// ---- slow-path helpers (unreachable: all classes m<=96; insurance only) ----
__device__ float dotg(const float* x, const float* y){
  float s = 0.f;
  for (int k = 0; k < D_; ++k) s = fmaf(x[k], y[k], s);
  return s;
}
__device__ float S_pair_g(const float* feat, int ga, int gb){
  const float* ra = feat + (size_t)ga * D_;
  const float* rb = feat + (size_t)gb * D_;
  float d = dotg(ra, rb);
  float na = 1.f / fmaxf(sqrtf(dotg(ra, ra)), 1e-12f);
  float nb = 1.f / fmaxf(sqrtf(dotg(rb, rb)), 1e-12f);
  return d * na * nb;
}

// ==== single cooperative kernel: full-width staged pipeline ====
__global__ __launch_bounds__(NT) void k_all(
    const float* __restrict__ feat, const float* __restrict__ cent,
    const int* __restrict__ labels, char* __restrict__ ws,
    float* __restrict__ out, int cap)
{
  cg::grid_group grid = cg::this_grid();
  const int bid = blockIdx.x;
  const int tid = threadIdx.x;
  const int wid = tid >> 6, lane = tid & 63;

  float* acc_g = (float*)(ws + 0);        // 2 floats
  int*   cnt_g = (int*)(ws + 64);         // 128
  float* cnv_g = (float*)(ws + 576);      // 128
  int*   mem_g = (int*)(ws + 1088);       // 128*96
  float* rn_g  = (float*)(ws + 50240);    // 128*96
  float* ecr_g = (float*)(ws + 99392);    // 128*96
  float* Sg_g  = (float*)(ws + 148544);   // cap floats

  __shared__ __align__(16) float Sl[P_CAP];   // 18240 B (fallback reuses as int[])
  __shared__ int   hist[NB_H];
  __shared__ int   poffs_l[C_ + 1], mloc[C_];
  __shared__ int   gid_l[M_CAP];
  __shared__ float ecv[M_CAP];
  __shared__ int   curs_sh;
  __shared__ float mnb[NW], mxb[NW], lo_sh, sF_sh;
  __shared__ int   B0_sh;
  __shared__ float thr_sh;
  __shared__ float redbuf[16];

  // ---- S0: per-class member compaction + row norms + EC dots (blocks 0..127) ----
  if (bid < C_){
    if (tid == 0) curs_sh = 0;
    __syncthreads();
    for (int i = tid; i < B_; i += NT){
      if (labels[i] == bid){
        int p = atomicAdd(&curs_sh, 1);
        if (p < M_CAP){ mem_g[bid * M_CAP + p] = i; gid_l[p] = i; }
      }
    }
    __syncthreads();
    const int mtot = curs_sh;
    if (tid == 0) cnt_g[bid] = mtot;
    const int mm = min(mtot, M_CAP);
    const float4* c4 = (const float4*)(cent + (size_t)bid * D_);
    for (int k = wid; k < mm; k += NW){
      int g = gid_l[k];
      const float4* r4 = (const float4*)(feat + (size_t)g * D_);
      float ss = 0.f, se = 0.f;
      for (int j = lane; j < D_ / 4; j += 64){
        float4 v = r4[j], cv = c4[j];
        ss += dot4(v, v); se += dot4(v, cv);
      }
      ss = wave_red(ss); se = wave_red(se);
      if (lane == 0){
        rn_g[bid * M_CAP + k] = 1.f / fmaxf(sqrtf(ss), 1e-12f);
        ecr_g[bid * M_CAP + k] = se;
      }
    }
    if (wid == 0){
      float cs = 0.f;
      for (int j = lane; j < D_ / 4; j += 64){ float4 cv = c4[j]; cs += dot4(cv, cv); }
      cs = wave_red(cs);
      if (lane == 0) cnv_g[bid] = 1.f / fmaxf(sqrtf(cs), 1e-12f);
    }
  } else if (bid == C_){
    if (tid == 0){ acc_g[0] = 0.f; acc_g[1] = 0.f; }
  }
  grid.sync();

  // ---- S1: pair dots, grid-strided over global pair index (all 2048 waves) ----
  if (tid == 0){
    int pacc = 0;
    for (int c = 0; c < C_; ++c){
      int m = cnt_g[c];
      mloc[c] = m; poffs_l[c] = pacc;
      if (m >= 2 && m <= M_CAP) pacc += m * (m - 1) / 2;
    }
    poffs_l[C_] = pacc;
  }
  __syncthreads();
  {
    const int tp = min(poffs_l[C_], cap);
    const int nw = (NBLK * NT) >> 6;
    for (int p = (bid * NT + tid) >> 6; p < tp; p += nw){
      int lo2 = 0, hi2 = C_;
      while (hi2 - lo2 > 1){ int mid = (lo2 + hi2) >> 1; if (poffs_l[mid] <= p) lo2 = mid; else hi2 = mid; }
      const int c2 = lo2;
      const int pl = p - poffs_l[c2];
      int a, b; decode_pair(pl, mloc[c2], &a, &b);
      const int ga = mem_g[c2 * M_CAP + a];
      const int gb = mem_g[c2 * M_CAP + b];
      const float4* r4 = (const float4*)(feat + (size_t)ga * D_);
      const float4* q4 = (const float4*)(feat + (size_t)gb * D_);
      float s = 0.f;
#pragma unroll
      for (int j = 0; j < 3; ++j){
        float4 x = r4[lane + 64 * j], y = q4[lane + 64 * j];
        s += dot4(x, y);
      }
      s = wave_red(s);
      if (lane == 0) Sg_g[p] = s * rn_g[c2 * M_CAP + a] * rn_g[c2 * M_CAP + b];
    }
  }
  grid.sync();

  // ---- S2: per-class median + loss (blocks 0..127) ----
  float lloss = 0.f, lw = 0.f;
  if (bid < C_){
    const int m = mloc[bid];
    const int pbase = poffs_l[bid];
    if (m >= 2){
      const int P = m * (m - 1) / 2;
      const int k0 = (P - 1) >> 1;
      const float wc = (float)m;
      const bool fast = (m <= M_CAP) && (pbase + P <= cap);
      if (fast){
        if (tid < m) ecv[tid] = ecr_g[bid * M_CAP + tid] * rn_g[bid * M_CAP + tid] * cnv_g[bid];
        for (int i = tid; i < NB_H; i += NT) hist[i] = 0;
        float pmn = 1e30f, pmx = -1e30f;
        for (int p = tid; p < P; p += NT){
          float s = Sg_g[pbase + p];
          Sl[p] = s;
          float pd = 1.f - clamp1(s);
          pmn = fminf(pmn, pd); pmx = fmaxf(pmx, pd);
        }
        pmn = wave_min(pmn); pmx = wave_max(pmx);
        if (lane == 0){ mnb[wid] = pmn; mxb[wid] = pmx; }
        __syncthreads();
        if (tid == 0){
          float mn = mnb[0], mx = mxb[0];
#pragma unroll
          for (int i = 1; i < NW; ++i){ mn = fminf(mn, mnb[i]); mx = fmaxf(mx, mxb[i]); }
          lo_sh = mn;
          sF_sh = (float)NB_H / fmaxf(mx - mn, 1e-20f);
        }
        __syncthreads();
        const float lo = lo_sh, sF = sF_sh;
        for (int p = tid; p < P; p += NT){
          float pd = 1.f - clamp1(Sl[p]);
          int bk = max(0, min(NB_H - 1, (int)((pd - lo) * sF)));
          atomicAdd(&hist[bk], 1);
        }
        __syncthreads();
        if (tid < 64){
          const int G = NB_H / 64;
          int loc[NB_H / 64];
          int ssum = 0;
          const int base = tid * G;
#pragma unroll
          for (int k = 0; k < G; ++k){ loc[k] = hist[base + k]; ssum += loc[k]; }
          int inc = ssum;
#pragma unroll
          for (int o = 1; o < 64; o <<= 1){
            int v = __shfl_up(inc, o, 64);
            if (tid >= o) inc += v;
          }
          int excl = inc - ssum;
          if (excl <= k0 && k0 < inc){
            int accq = excl;
#pragma unroll
            for (int k = 0; k < G; ++k){
              if (accq + loc[k] > k0){ B0_sh = base + k; break; }
              accq += loc[k];
            }
          }
        }
        __syncthreads();
        const int bsel = B0_sh;
        for (int p = tid; p < P; p += NT){
          float pdp = 1.f - clamp1(Sl[p]);
          int bk = max(0, min(NB_H - 1, (int)((pdp - lo) * sF)));
          if (bk == bsel){
            int lt = 0, eq = 0;
#pragma unroll 4
            for (int q = 0; q < P; ++q){
              float pdq = 1.f - clamp1(Sl[q]);
              lt += (pdq < pdp); eq += (pdq == pdp);
            }
            if (lt <= k0 && k0 < lt + eq) thr_sh = pdp;
          }
        }
        __syncthreads();
        const float thr = thr_sh;
        for (int p = tid; p < P; p += NT){
          float S = Sl[p];
          float pd = 1.f - clamp1(S);
          if (pd > thr){
            int a, b; decode_pair(p, m, &a, &b);
            int ga = mem_g[bid * M_CAP + a], gb = mem_g[bid * M_CAP + b];
            float ea = ecv[a], eb = ecv[b];
            int i, j; float eci, ecj;
            if (ga < gb){ i = ga; j = gb; eci = ea; ecj = eb; }
            else        { i = gb; j = ga; eci = eb; ecj = ea; }
            float r = rand_ij((unsigned)i * (unsigned)B_ + (unsigned)j);
            float omr = 1.f - r;
            float n2 = r * r + omr * omr + 2.f * r * omr * S;   // raw S
            float nrm = fmaxf(sqrtf(fmaxf(n2, 0.f)), 1e-12f);
            float dt = clamp1((r * eci + omr * ecj) / nrm);
            lloss += wc * (1.f - dt);
            lw += wc;
          }
        }
      } else {
        // correctness-only fallback (m > M_CAP or pair-buffer overflow)
        int* mem = (int*)Sl;                  // 4560 ints >= B_ members? m<=4096 fits
        if (tid == 0) B0_sh = 0;
        __syncthreads();
        for (int i = tid; i < B_; i += NT)
          if (labels[i] == bid){ int p = atomicAdd(&B0_sh, 1); if (p < P_CAP) mem[p] = i; }
        __syncthreads();
        const float* cc = cent + (size_t)bid * D_;
        const float cno = 1.f / fmaxf(sqrtf(dotg(cc, cc)), 1e-12f);
        for (int p = tid; p < P; p += NT){
          int a, b; decode_pair(p, m, &a, &b);
          float pdp = 1.f - clamp1(S_pair_g(feat, mem[a], mem[b]));
          int lt = 0, eq = 0;
          for (int q = 0; q < P; ++q){
            int a2, b2; decode_pair(q, m, &a2, &b2);
            float pdq = 1.f - clamp1(S_pair_g(feat, mem[a2], mem[b2]));
            lt += (pdq < pdp); eq += (pdq == pdp);
          }
          if (lt <= k0 && k0 < lt + eq) thr_sh = pdp;
        }
        __syncthreads();
        const float thr = thr_sh;
        for (int p = tid; p < P; p += NT){
          int a, b; decode_pair(p, m, &a, &b);
          int ga = mem[a], gb = mem[b];
          float S = S_pair_g(feat, ga, gb);
          float pd = 1.f - clamp1(S);
          if (pd > thr){
            if (ga > gb){ int t2 = ga; ga = gb; gb = t2; }
            const float* ra = feat + (size_t)ga * D_;
            const float* rb = feat + (size_t)gb * D_;
            float eci = dotg(ra, cc) / fmaxf(sqrtf(dotg(ra, ra)), 1e-12f) * cno;
            float ecj = dotg(rb, cc) / fmaxf(sqrtf(dotg(rb, rb)), 1e-12f) * cno;
            float r = rand_ij((unsigned)ga * (unsigned)B_ + (unsigned)gb);
            float omr = 1.f - r;
            float n2 = r * r + omr * omr + 2.f * r * omr * S;
            float nrm = fmaxf(sqrtf(fmaxf(n2, 0.f)), 1e-12f);
            float dt = clamp1((r * eci + omr * ecj) / nrm);
            lloss += wc * (1.f - dt);
            lw += wc;
          }
        }
      }
    }
  }

  // block reduce + device accumulate
  lloss = wave_red(lloss); lw = wave_red(lw);
  if (lane == 0){ redbuf[wid] = lloss; redbuf[8 + wid] = lw; }
  __syncthreads();
  if (tid == 0){
    float tl = 0.f, tw = 0.f;
#pragma unroll
    for (int i = 0; i < NW; ++i){ tl += redbuf[i]; tw += redbuf[8 + i]; }
    if (tl != 0.f || tw != 0.f){
      atomicAdd(&acc_g[0], tl);
      atomicAdd(&acc_g[1], tw);
    }
  }
  grid.sync();
  if (bid == 0 && tid == 0){
    float l = acc_g[0], w = acc_g[1];
    out[0] = (w > 0.f) ? (l / w) : 0.f;
  }
}

extern "C" void kernel_launch(void* const* d_in, const int* in_sizes, int n_in,
                              void* d_out, int out_size, void* d_ws, size_t ws_size,
                              hipStream_t stream)
{
  const float* feat   = (const float*)d_in[0];
  const float* cent   = (const float*)d_in[1];
  const int*   labels = (const int*)d_in[2];
  // d_in[3] = cam_ids: unused by the reference computation.

  char* ws = (char*)d_ws;
  float* out = (float*)d_out;
  long long avail = (long long)ws_size - 148544;
  int cap = (avail > 0) ? (int)((avail / 4 < (long long)SG_CAP) ? avail / 4 : (long long)SG_CAP) : 0;

  void* args[] = { (void*)&feat, (void*)&cent, (void*)&labels,
                   (void*)&ws, (void*)&out, (void*)&cap };
  hipLaunchCooperativeKernel((void*)k_all, dim3(NBLK), dim3(NT), args, 0, stream);
}

// Round 10
// 204.966 us; speedup vs baseline: 1.3244x; 1.3244x over previous
//
#include <hip/hip_runtime.h>

#define B_ 4096
#define C_ 128
#define D_ 768
#define NT 1024
#define NW (NT/64)                  // 16 waves
#define M_CAP 96
#define P_CAP (M_CAP*(M_CAP-1)/2)   // 4560
#define NB_H 1024

__device__ __forceinline__ float wave_red(float v){
#pragma unroll
  for (int o = 32; o > 0; o >>= 1) v += __shfl_down(v, o, 64);
  return v;
}
__device__ __forceinline__ float wave_min(float v){
#pragma unroll
  for (int o = 32; o > 0; o >>= 1) v = fminf(v, __shfl_down(v, o, 64));
  return v;
}
__device__ __forceinline__ float wave_max(float v){
#pragma unroll
  for (int o = 32; o > 0; o >>= 1) v = fmaxf(v, __shfl_down(v, o, 64));
  return v;
}
__device__ __forceinline__ float clamp1(float x){ return fminf(fmaxf(x, -1.f), 1.f); }
__device__ __forceinline__ unsigned rotl32(unsigned x, int r){ return (x << r) | (x >> (32 - r)); }
__device__ __forceinline__ float dot4(float4 a, float4 b){
  return fmaf(a.x, b.x, fmaf(a.y, b.y, fmaf(a.z, b.z, a.w * b.w)));
}

// jax.random.uniform(jax.random.key(1),(B,B)) element n: Threefry-2x32 key (0,1),
// counters split in halves. Bit-exact (verified rounds 1-9: absmax 0.0).
__device__ float rand_ij(unsigned n){
  const unsigned half = (unsigned)B_ * (unsigned)B_ / 2u;
  unsigned c0, c1; bool hi;
  if (n < half){ c0 = n; c1 = n + half; hi = false; }
  else         { c0 = n - half; c1 = n; hi = true; }
  const unsigned K0 = 0u, K1 = 1u, K2 = 0x1BD11BDBu;
  unsigned x0 = c0 + K0, x1 = c1 + K1;
#define TFR(r) { x0 += x1; x1 = rotl32(x1, (r)); x1 ^= x0; }
  TFR(13) TFR(15) TFR(26) TFR(6)  x0 += K1; x1 += K2 + 1u;
  TFR(17) TFR(29) TFR(16) TFR(24) x0 += K2; x1 += K0 + 2u;
  TFR(13) TFR(15) TFR(26) TFR(6)  x0 += K0; x1 += K1 + 3u;
  TFR(17) TFR(29) TFR(16) TFR(24) x0 += K1; x1 += K2 + 4u;
  TFR(13) TFR(15) TFR(26) TFR(6)  x0 += K2; x1 += K0 + 5u;
#undef TFR
  unsigned bits = hi ? x1 : x0;
  return __uint_as_float((bits >> 9) | 0x3F800000u) - 1.0f;
}

// p -> (a,b), a<b<m, row-major upper-tri. before(a) = a*(2m-1-a)/2.
__device__ __forceinline__ void decode_pair(int p, int m, int* a_, int* b_){
  float fm = (float)(2*m - 1);
  int a = (int)((fm - sqrtf(fm*fm - 8.0f*(float)p)) * 0.5f);
  a = max(0, min(a, m - 2));
  while (a > 0 && (a*(2*m - 1 - a))/2 > p) --a;
  while (((a + 1)*(2*m - 2 - a))/2 <= p) ++a;
  *a_ = a;
  *b_ = a + 1 + (p - (a*(2*m - 1 - a))/2);
}

// ---- slow-path helpers (unreachable: all classes m<=96; insurance only) ----
__device__ float dotg(const float* x, const float* y){
  float s = 0.f;
  for (int k = 0; k < D_; ++k) s = fmaf(x[k], y[k], s);
  return s;
}
__device__ float S_pair_g(const float* feat, int ga, int gb){
  const float* ra = feat + (size_t)ga * D_;
  const float* rb = feat + (size_t)gb * D_;
  float d = dotg(ra, rb);
  float na = 1.f / fmaxf(sqrtf(dotg(ra, ra)), 1e-12f);
  float nb = 1.f / fmaxf(sqrtf(dotg(rb, rb)), 1e-12f);
  return d * na * nb;
}

// ==== one block per class, 1024 threads, direct-from-L2 wave-per-pair dots ====
__global__ __launch_bounds__(NT) void k_all(
    const float* __restrict__ feat, const float* __restrict__ cent,
    const int* __restrict__ labels,
    float* __restrict__ acc2, int* __restrict__ done, float* __restrict__ out)
{
  const int c = blockIdx.x;
  const int tid = threadIdx.x;
  const int wid = tid >> 6, lane = tid & 63;

  __shared__ __align__(16) float Sl[P_CAP];   // 18240 B (fallback reuses as int[])
  __shared__ int   hist[NB_H];
  __shared__ int   gid_l[M_CAP];
  __shared__ float rns[M_CAP];
  __shared__ float ecs[M_CAP];
  __shared__ int   curs_sh;
  __shared__ float cn_sh;
  __shared__ float mnb[NW], mxb[NW], lo_sh, sF_sh;
  __shared__ int   B0_sh;
  __shared__ float thr_sh;
  __shared__ float redbuf[2 * NW];

  // ---- phase A: compact members + zero hist ----
  if (tid == 0) curs_sh = 0;
  for (int i = tid; i < NB_H; i += NT) hist[i] = 0;
  __syncthreads();
  for (int i = tid; i < B_; i += NT){
    if (labels[i] == c){
      int p = atomicAdd(&curs_sh, 1);
      if (p < M_CAP) gid_l[p] = i;
    }
  }
  __syncthreads();
  const int m = curs_sh;

  float lloss = 0.f, lw = 0.f;

  if (m >= 2 && m <= M_CAP){
    const int P = m * (m - 1) / 2;
    const int k0 = (P - 1) >> 1;
    const float wc = (float)m;
    const float4* c4 = (const float4*)(cent + (size_t)c * D_);

    // ---- phase B: wave-per-row rnorm + raw EC (reads warm the L2 rows) ----
    for (int k = wid; k < m; k += NW){
      const float4* r4 = (const float4*)(feat + (size_t)gid_l[k] * D_);
      float ss = 0.f, se = 0.f;
#pragma unroll
      for (int j = 0; j < 3; ++j){
        float4 v = r4[lane + 64 * j], cv = c4[lane + 64 * j];
        ss += dot4(v, v); se += dot4(v, cv);
      }
      ss = wave_red(ss); se = wave_red(se);
      if (lane == 0){
        rns[k] = 1.f / fmaxf(sqrtf(ss), 1e-12f);
        ecs[k] = se;                             // raw; scaled below
      }
    }
    if (wid == 0){
      float cs = 0.f;
#pragma unroll
      for (int j = 0; j < 3; ++j){ float4 cv = c4[lane + 64 * j]; cs += dot4(cv, cv); }
      cs = wave_red(cs);
      if (lane == 0) cn_sh = 1.f / fmaxf(sqrtf(cs), 1e-12f);
    }
    __syncthreads();
    if (tid < m) ecs[tid] = ecs[tid] * rns[tid] * cn_sh;

    // ---- phase C: wave-per-pair dots straight from L2, no barriers inside ----
    for (int p = wid; p < P; p += NW){
      int a, b; decode_pair(p, m, &a, &b);
      const float4* r4 = (const float4*)(feat + (size_t)gid_l[a] * D_);
      const float4* q4 = (const float4*)(feat + (size_t)gid_l[b] * D_);
      float s = 0.f;
#pragma unroll
      for (int j = 0; j < 3; ++j) s += dot4(r4[lane + 64 * j], q4[lane + 64 * j]);
      s = wave_red(s);
      if (lane == 0) Sl[p] = s * rns[a] * rns[b];
    }
    __syncthreads();

    // ---- phase D: adaptive histogram rank-select (bit-exact threshold) ----
    float pmn = 1e30f, pmx = -1e30f;
    for (int p = tid; p < P; p += NT){
      float pd = 1.f - clamp1(Sl[p]);
      pmn = fminf(pmn, pd); pmx = fmaxf(pmx, pd);
    }
    pmn = wave_min(pmn); pmx = wave_max(pmx);
    if (lane == 0){ mnb[wid] = pmn; mxb[wid] = pmx; }
    __syncthreads();
    if (tid == 0){
      float mn = mnb[0], mx = mxb[0];
#pragma unroll
      for (int i = 1; i < NW; ++i){ mn = fminf(mn, mnb[i]); mx = fmaxf(mx, mxb[i]); }
      lo_sh = mn;
      sF_sh = (float)NB_H / fmaxf(mx - mn, 1e-20f);
    }
    __syncthreads();
    const float lo = lo_sh, sF = sF_sh;
    for (int p = tid; p < P; p += NT){
      float pd = 1.f - clamp1(Sl[p]);
      int bk = max(0, min(NB_H - 1, (int)((pd - lo) * sF)));
      atomicAdd(&hist[bk], 1);
    }
    __syncthreads();
    if (tid < 64){
      const int G = NB_H / 64;                   // 16 buckets per lane
      int loc[NB_H / 64];
      int ssum = 0;
      const int base = tid * G;
#pragma unroll
      for (int k = 0; k < G; ++k){ loc[k] = hist[base + k]; ssum += loc[k]; }
      int inc = ssum;
#pragma unroll
      for (int o = 1; o < 64; o <<= 1){
        int v = __shfl_up(inc, o, 64);
        if (tid >= o) inc += v;
      }
      int excl = inc - ssum;
      if (excl <= k0 && k0 < inc){
        int accq = excl;
#pragma unroll
        for (int k = 0; k < G; ++k){
          if (accq + loc[k] > k0){ B0_sh = base + k; break; }
          accq += loc[k];
        }
      }
    }
    __syncthreads();
    const int bsel = B0_sh;
    for (int p = tid; p < P; p += NT){
      float pdp = 1.f - clamp1(Sl[p]);
      int bk = max(0, min(NB_H - 1, (int)((pdp - lo) * sF)));
      if (bk == bsel){
        int lt = 0, eq = 0;
        for (int q = 0; q < P; ++q){
          float pdq = 1.f - clamp1(Sl[q]);
          lt += (pdq < pdp); eq += (pdq == pdp);
        }
        if (lt <= k0 && k0 < lt + eq) thr_sh = pdp;
      }
    }
    __syncthreads();
    const float thr = thr_sh;

    // ---- phase E: loss over selected pairs ----
    for (int p = tid; p < P; p += NT){
      float S = Sl[p];
      float pd = 1.f - clamp1(S);
      if (pd > thr){
        int a, b; decode_pair(p, m, &a, &b);
        int ga = gid_l[a], gb = gid_l[b];
        float ea = ecs[a], eb = ecs[b];
        int i, j; float eci, ecj;
        if (ga < gb){ i = ga; j = gb; eci = ea; ecj = eb; }
        else        { i = gb; j = ga; eci = eb; ecj = ea; }
        float r = rand_ij((unsigned)i * (unsigned)B_ + (unsigned)j);
        float omr = 1.f - r;
        float n2 = r * r + omr * omr + 2.f * r * omr * S;     // raw S
        float nrm = fmaxf(sqrtf(fmaxf(n2, 0.f)), 1e-12f);
        float dt = clamp1((r * eci + omr * ecj) / nrm);
        lloss += wc * (1.f - dt);
        lw += wc;
      }
    }
  } else if (m > M_CAP){
    // correctness-only fallback (impossible here: max m ~47, verified R1-R9)
    int* mem = (int*)Sl;                         // 4560 ints >= any m <= 4096
    if (tid == 0) B0_sh = 0;
    __syncthreads();
    for (int i = tid; i < B_; i += NT)
      if (labels[i] == c){ int p = atomicAdd(&B0_sh, 1); mem[p] = i; }
    __syncthreads();
    const int P = m * (m - 1) / 2;
    const int k0 = (P - 1) >> 1;
    const float wc = (float)m;
    const float* cc = cent + (size_t)c * D_;
    const float cno = 1.f / fmaxf(sqrtf(dotg(cc, cc)), 1e-12f);
    for (int p = tid; p < P; p += NT){
      int a, b; decode_pair(p, m, &a, &b);
      float pdp = 1.f - clamp1(S_pair_g(feat, mem[a], mem[b]));
      int lt = 0, eq = 0;
      for (int q = 0; q < P; ++q){
        int a2, b2; decode_pair(q, m, &a2, &b2);
        float pdq = 1.f - clamp1(S_pair_g(feat, mem[a2], mem[b2]));
        lt += (pdq < pdp); eq += (pdq == pdp);
      }
      if (lt <= k0 && k0 < lt + eq) thr_sh = pdp;
    }
    __syncthreads();
    const float thr = thr_sh;
    for (int p = tid; p < P; p += NT){
      int a, b; decode_pair(p, m, &a, &b);
      int ga = mem[a], gb = mem[b];
      float S = S_pair_g(feat, ga, gb);
      float pd = 1.f - clamp1(S);
      if (pd > thr){
        if (ga > gb){ int t2 = ga; ga = gb; gb = t2; }
        const float* ra = feat + (size_t)ga * D_;
        const float* rb = feat + (size_t)gb * D_;
        float eci = dotg(ra, cc) / fmaxf(sqrtf(dotg(ra, ra)), 1e-12f) * cno;
        float ecj = dotg(rb, cc) / fmaxf(sqrtf(dotg(rb, rb)), 1e-12f) * cno;
        float r = rand_ij((unsigned)ga * (unsigned)B_ + (unsigned)gb);
        float omr = 1.f - r;
        float n2 = r * r + omr * omr + 2.f * r * omr * S;
        float nrm = fmaxf(sqrtf(fmaxf(n2, 0.f)), 1e-12f);
        float dt = clamp1((r * eci + omr * ecj) / nrm);
        lloss += wc * (1.f - dt);
        lw += wc;
      }
    }
  }
  // m < 2: nothing to add

  // ---- phase F: block reduce + device accumulate + last-block finalize ----
  lloss = wave_red(lloss); lw = wave_red(lw);
  if (lane == 0){ redbuf[wid] = lloss; redbuf[NW + wid] = lw; }
  __syncthreads();
  if (tid == 0){
    float tl = 0.f, tw = 0.f;
#pragma unroll
    for (int i = 0; i < NW; ++i){ tl += redbuf[i]; tw += redbuf[NW + i]; }
    if (tl != 0.f || tw != 0.f){
      atomicAdd(&acc2[0], tl);
      atomicAdd(&acc2[1], tw);
    }
    __threadfence();
    int old = atomicAdd(done, 1);
    if (old == C_ - 1){
      float l = atomicAdd(&acc2[0], 0.f);
      float w = atomicAdd(&acc2[1], 0.f);
      out[0] = (w > 0.f) ? (l / w) : 0.f;
    }
  }
}

extern "C" void kernel_launch(void* const* d_in, const int* in_sizes, int n_in,
                              void* d_out, int out_size, void* d_ws, size_t ws_size,
                              hipStream_t stream)
{
  const float* feat   = (const float*)d_in[0];
  const float* cent   = (const float*)d_in[1];
  const int*   labels = (const int*)d_in[2];
  // d_in[3] = cam_ids: unused by the reference computation.

  char* ws = (char*)d_ws;
  float* acc2 = (float*)(ws + 0);   // loss, wsum
  int*   done = (int*)(ws + 8);

  hipMemsetAsync(ws, 0, 16, stream);
  k_all<<<C_, NT, 0, stream>>>(feat, cent, labels, acc2, done, (float*)d_out);
}

// Round 11
// 173.465 us; speedup vs baseline: 1.5649x; 1.1816x over previous
//
#include <hip/hip_runtime.h>

#define B_ 4096
#define C_ 128
#define D_ 768
#define HD 384                      // half of D
#define NBLK 256
#define NT 1024
#define NW (NT/64)                  // 16 waves
#define M_CAP 80
#define P_CAP (M_CAP*(M_CAP-1)/2)   // 3160
#define SROW4 97                    // row stride in float4 (388 floats)
#define GPPT ((P_CAP+NT-1)/NT)      // 4
#define LPT (B_/NT)                 // 4 labels per thread
#define SRAW_OFF 1024
#define Z_CAP (300*1024)            // zeroed Sraw bytes (covers sumP~63.5K floats)

__device__ __forceinline__ float wave_red(float v){
#pragma unroll
  for (int o = 32; o > 0; o >>= 1) v += __shfl_down(v, o, 64);
  return v;
}
__device__ __forceinline__ float wave_min(float v){
#pragma unroll
  for (int o = 32; o > 0; o >>= 1) v = fminf(v, __shfl_down(v, o, 64));
  return v;
}
__device__ __forceinline__ float wave_max(float v){
#pragma unroll
  for (int o = 32; o > 0; o >>= 1) v = fmaxf(v, __shfl_down(v, o, 64));
  return v;
}
__device__ __forceinline__ float clamp1(float x){ return fminf(fmaxf(x, -1.f), 1.f); }
__device__ __forceinline__ unsigned rotl32(unsigned x, int r){ return (x << r) | (x >> (32 - r)); }
__device__ __forceinline__ float dot4(float4 a, float4 b){
  return fmaf(a.x, b.x, fmaf(a.y, b.y, fmaf(a.z, b.z, a.w * b.w)));
}

// jax.random.uniform(jax.random.key(1),(B,B)) element n: Threefry-2x32 key (0,1),
// counters split in halves. Bit-exact (verified rounds 1-10: absmax 0.0).
__device__ float rand_ij(unsigned n){
  const unsigned half = (unsigned)B_ * (unsigned)B_ / 2u;
  unsigned c0, c1; bool hi;
  if (n < half){ c0 = n; c1 = n + half; hi = false; }
  else         { c0 = n - half; c1 = n; hi = true; }
  const unsigned K0 = 0u, K1 = 1u, K2 = 0x1BD11BDBu;
  unsigned x0 = c0 + K0, x1 = c1 + K1;
#define TFR(r) { x0 += x1; x1 = rotl32(x1, (r)); x1 ^= x0; }
  TFR(13) TFR(15) TFR(26) TFR(6)  x0 += K1; x1 += K2 + 1u;
  TFR(17) TFR(29) TFR(16) TFR(24) x0 += K2; x1 += K0 + 2u;
  TFR(13) TFR(15) TFR(26) TFR(6)  x0 += K0; x1 += K1 + 3u;
  TFR(17) TFR(29) TFR(16) TFR(24) x0 += K1; x1 += K2 + 4u;
  TFR(13) TFR(15) TFR(26) TFR(6)  x0 += K2; x1 += K0 + 5u;
#undef TFR
  unsigned bits = hi ? x1 : x0;
  return __uint_as_float((bits >> 9) | 0x3F800000u) - 1.0f;
}

// p -> (a,b), a<b<m, row-major upper-tri. before(a) = a*(2m-1-a)/2.
__device__ __forceinline__ void decode_pair(int p, int m, int* a_, int* b_){
  float fm = (float)(2*m - 1);
  int a = (int)((fm - sqrtf(fm*fm - 8.0f*(float)p)) * 0.5f);
  a = max(0, min(a, m - 2));
  while (a > 0 && (a*(2*m - 1 - a))/2 > p) --a;
  while (((a + 1)*(2*m - 2 - a))/2 <= p) ++a;
  *a_ = a;
  *b_ = a + 1 + (p - (a*(2*m - 1 - a))/2);
}

// ---- slow-path helpers (unreachable on this dataset; insurance only) ----
__device__ float dotg(const float* x, const float* y){
  float s = 0.f;
  for (int k = 0; k < D_; ++k) s = fmaf(x[k], y[k], s);
  return s;
}
__device__ float S_pair_g(const float* feat, int ga, int gb){
  const float* ra = feat + (size_t)ga * D_;
  const float* rb = feat + (size_t)gb * D_;
  float d = dotg(ra, rb);
  float na = 1.f / fmaxf(sqrtf(dotg(ra, ra)), 1e-12f);
  float nb = 1.f / fmaxf(sqrtf(dotg(rb, rb)), 1e-12f);
  return d * na * nb;
}

// ==== 256 blocks: 2 per class, D-split gram; 2nd finisher does select+loss ====
__global__ __launch_bounds__(NT) void k_all(
    const float* __restrict__ feat, const float* __restrict__ cent,
    const int* __restrict__ labels, char* __restrict__ ws,
    float* __restrict__ out, long long zcap)
{
  const int bid = blockIdx.x;
  const int c = bid >> 1, h = bid & 1;
  const int tid = threadIdx.x;
  const int wid = tid >> 6, lane = tid & 63;

  float* acc2 = (float*)(ws + 0);
  int*   done = (int*)(ws + 8);
  int*   fin  = (int*)(ws + 64);          // 128 ints
  float* Sraw = (float*)(ws + SRAW_OFF);

  __shared__ __align__(16) float tile[M_CAP * SROW4 * 4];   // 124160 B; overlaid below
  float*          Sl   = tile;                               // P_CAP
  float*          Pd   = tile + P_CAP;                       // P_CAP
  unsigned short* fidx = (unsigned short*)(tile + 2*P_CAP);  // P_CAP
  __shared__ int   gid[M_CAP];
  __shared__ float rns[M_CAP], ecs[M_CAP];
  __shared__ int   tcnt[NT];
  __shared__ int   wtot[NW];
  __shared__ int   hcnt[C_];
  __shared__ int   wcnt[NW * 64];
  __shared__ float mnb[NW], mxb[NW];
  __shared__ float redbuf[2 * NW];
  __shared__ int   m_sh, poffs_sh, totP_sh, old_sh, B0_sh, ex_sh, B1_sh;
  __shared__ float cn_sh, lo_sh, sF_sh, thr_sh;

  // ---- phase A: histogram + STABLE member compaction (identical in both blocks) ----
  if (tid < C_) hcnt[tid] = 0;
  __syncthreads();
  int myIdx[LPT]; int myc = 0;
#pragma unroll
  for (int k = 0; k < LPT; ++k){
    int i = tid * LPT + k;
    int lb = labels[i];
    atomicAdd(&hcnt[lb], 1);
    if (lb == c) myIdx[myc++] = i;
  }
  tcnt[tid] = myc;
  // wave-inclusive scan of per-thread counts
  int incl = myc;
#pragma unroll
  for (int o = 1; o < 64; o <<= 1){
    int v = __shfl_up(incl, o, 64);
    if (lane >= o) incl += v;
  }
  if (lane == 63) wtot[wid] = incl;
  __syncthreads();
  {
    int wpre = 0;
    for (int w = 0; w < wid; ++w) wpre += wtot[w];
    int base = wpre + incl - myc;
    for (int t = 0; t < myc; ++t){
      int pos = base + t;
      if (pos < M_CAP) gid[pos] = myIdx[t];     // ascending order: deterministic
    }
  }
  // per-class pair-offset prefix (wave 0)
  if (wid == 0){
    int h0 = hcnt[lane], h1 = hcnt[lane + 64];
    int hm0 = min(h0, M_CAP), hm1 = min(h1, M_CAP);   // only fast classes store pairs
    int p0 = (h0 >= 2 && h0 <= M_CAP) ? hm0*(hm0-1)/2 : 0;
    int p1 = (h1 >= 2 && h1 <= M_CAP) ? hm1*(hm1-1)/2 : 0;
    int s0 = p0;
#pragma unroll
    for (int o = 1; o < 64; o <<= 1){ int v = __shfl_up(s0, o, 64); if (lane >= o) s0 += v; }
    int tot0 = __shfl(s0, 63);
    int s1 = p1;
#pragma unroll
    for (int o = 1; o < 64; o <<= 1){ int v = __shfl_up(s1, o, 64); if (lane >= o) s1 += v; }
    if (c < 64){ if (lane == c) poffs_sh = s0 - p0; }
    else       { if (lane == c - 64) poffs_sh = tot0 + s1 - p1; }
    if (lane == 63) totP_sh = tot0 + s1;
  }
  if (tid == 0) m_sh = hcnt[c];
  __syncthreads();

  const int m = m_sh;
  const bool wsOK = ((long long)totP_sh * 4 <= zcap);
  const bool fast = (m >= 2) && (m <= M_CAP) && wsOK;
  float lloss = 0.f, lw = 0.f;

  if (fast){
    const int P = m * (m - 1) / 2;
    const int k0 = (P - 1) >> 1;
    const float wc = (float)m;
    const int poffs = poffs_sh;

    // ---- phase B: single-shot staging of all rows' D-half ----
    for (int e = tid; e < m * (HD/4); e += NT){
      int r = e / (HD/4), jb = e - r * (HD/4);
      ((float4*)tile)[r * SROW4 + jb] =
          ((const float4*)(feat + (size_t)gid[r] * D_ + h * HD))[jb];
    }
    __syncthreads();

    // ---- phase C: thread-per-pair half-D dots, atomic-add into Sraw ----
    int pa[GPPT];
    float acc[GPPT];
#pragma unroll
    for (int s = 0; s < GPPT; ++s){
      pa[s] = -1; acc[s] = 0.f;
      int p = tid + s * NT;
      if (p < P){
        int a, b; decode_pair(p, m, &a, &b);
        pa[s] = (a << 8) | b;       // a,b < 80 fit
      }
    }
#pragma unroll
    for (int s = 0; s < GPPT; ++s){
      if (pa[s] >= 0){
        const float4* A = (const float4*)tile + (pa[s] >> 8) * SROW4;
        const float4* Bp = (const float4*)tile + (pa[s] & 255) * SROW4;
        float sum = 0.f;
#pragma unroll 8
        for (int jb = 0; jb < HD/4; ++jb) sum += dot4(A[jb], Bp[jb]);
        acc[s] = sum;
      }
    }
#pragma unroll
    for (int s = 0; s < GPPT; ++s)
      if (pa[s] >= 0) atomicAdd(&Sraw[poffs + tid + s * NT], acc[s]);

    // release: all writes visible, then bump per-class finish counter
    __threadfence();
    __syncthreads();
    if (tid == 0) old_sh = atomicAdd(&fin[c], 1);
    __syncthreads();

    if (old_sh == 1){
      // ---- finisher: summed S -> rnorm/EC -> select -> loss ----
      for (int p = tid; p < P; p += NT) Sl[p] = Sraw[poffs + p];
      const float4* c4 = (const float4*)(cent + (size_t)c * D_);
      for (int k = wid; k < m; k += NW){
        const float4* r4 = (const float4*)(feat + (size_t)gid[k] * D_);
        float ss = 0.f, se = 0.f;
#pragma unroll
        for (int j = 0; j < 3; ++j){
          float4 v = r4[lane + 64 * j], cv = c4[lane + 64 * j];
          ss += dot4(v, v); se += dot4(v, cv);
        }
        ss = wave_red(ss); se = wave_red(se);
        if (lane == 0){
          rns[k] = 1.f / fmaxf(sqrtf(ss), 1e-12f);
          ecs[k] = se;
        }
      }
      if (wid == 0){
        float cs = 0.f;
#pragma unroll
        for (int j = 0; j < 3; ++j){ float4 cv = c4[lane + 64 * j]; cs += dot4(cv, cv); }
        cs = wave_red(cs);
        if (lane == 0) cn_sh = 1.f / fmaxf(sqrtf(cs), 1e-12f);
      }
      __syncthreads();
      if (tid < m) ecs[tid] = ecs[tid] * rns[tid] * cn_sh;
      __syncthreads();

      // normalize + pd + min/max
      float pmn = 1e30f, pmx = -1e30f;
      for (int p = tid; p < P; p += NT){
        int a, b; decode_pair(p, m, &a, &b);
        float S = Sl[p] * rns[a] * rns[b];
        Sl[p] = S;
        float pd = 1.f - clamp1(S);
        Pd[p] = pd;
        pmn = fminf(pmn, pd); pmx = fmaxf(pmx, pd);
      }
      pmn = wave_min(pmn); pmx = wave_max(pmx);
      if (lane == 0){ mnb[wid] = pmn; mxb[wid] = pmx; }
      __syncthreads();
      if (tid == 0){
        float mn = mnb[0], mx = mxb[0];
#pragma unroll
        for (int i = 1; i < NW; ++i){ mn = fminf(mn, mnb[i]); mx = fmaxf(mx, mxb[i]); }
        lo_sh = mn;
        sF_sh = 4096.f / fmaxf(mx - mn, 1e-20f);
      }
      __syncthreads();
      const float lo = lo_sh, sF = sF_sh;

      // two-level ballot rank-select (R7-proven)
      const int nch = (P + NT - 1) / NT;
      int cl = 0;
      for (int t = 0; t < nch; ++t){
        int p = tid + t * NT;
        int bkt = -1;
        if (p < P){
          int f = max(0, min(4095, (int)((Pd[p] - lo) * sF)));
          fidx[p] = (unsigned short)f;
          bkt = f >> 6;
        }
#pragma unroll
        for (int k = 0; k < 64; ++k){
          unsigned long long msk = __ballot(bkt == k);
          if (lane == k) cl += __popcll(msk);
        }
      }
      wcnt[wid*64 + lane] = cl;
      __syncthreads();
      if (tid < 64){
        int tot = 0;
#pragma unroll
        for (int w = 0; w < NW; ++w) tot += wcnt[w*64 + tid];
        int inc = tot;
#pragma unroll
        for (int o = 1; o < 64; o <<= 1){
          int v = __shfl_up(inc, o, 64);
          if (tid >= o) inc += v;
        }
        int excl = inc - tot;
        if (excl <= k0 && k0 < inc){ B0_sh = tid; ex_sh = excl; }
      }
      __syncthreads();
      const int Bsel0 = B0_sh;
      const int kt = k0 - ex_sh;
      cl = 0;
      for (int t = 0; t < nch; ++t){
        int p = tid + t * NT;
        int bkt = -1;
        if (p < P){
          int f = fidx[p];
          if ((f >> 6) == Bsel0) bkt = f & 63;
        }
#pragma unroll
        for (int k = 0; k < 64; ++k){
          unsigned long long msk = __ballot(bkt == k);
          if (lane == k) cl += __popcll(msk);
        }
      }
      wcnt[wid*64 + lane] = cl;
      __syncthreads();
      if (tid < 64){
        int tot = 0;
#pragma unroll
        for (int w = 0; w < NW; ++w) tot += wcnt[w*64 + tid];
        int inc = tot;
#pragma unroll
        for (int o = 1; o < 64; o <<= 1){
          int v = __shfl_up(inc, o, 64);
          if (tid >= o) inc += v;
        }
        int excl = inc - tot;
        if (excl <= kt && kt < inc) B1_sh = tid;
      }
      __syncthreads();
      const int fsel = (Bsel0 << 6) | B1_sh;
      for (int p = tid; p < P; p += NT){
        if (fidx[p] == (unsigned short)fsel){
          const float pdp = Pd[p];
          int lt = 0, eq = 0;
          for (int q = 0; q < P; ++q){
            float pdq = Pd[q];
            lt += (pdq < pdp); eq += (pdq == pdp);
          }
          if (lt <= k0 && k0 < lt + eq) thr_sh = pdp;
        }
      }
      __syncthreads();
      const float thr = thr_sh;

      for (int p = tid; p < P; p += NT){
        float pd = Pd[p];
        if (pd > thr){
          float S = Sl[p];
          int a, b; decode_pair(p, m, &a, &b);
          int ga = gid[a], gb = gid[b];
          float ea = ecs[a], eb = ecs[b];
          int i, j; float eci, ecj;
          if (ga < gb){ i = ga; j = gb; eci = ea; ecj = eb; }
          else        { i = gb; j = ga; eci = eb; ecj = ea; }
          float r = rand_ij((unsigned)i * (unsigned)B_ + (unsigned)j);
          float omr = 1.f - r;
          float n2 = r * r + omr * omr + 2.f * r * omr * S;   // raw S
          float nrm = fmaxf(sqrtf(fmaxf(n2, 0.f)), 1e-12f);
          float dt = clamp1((r * eci + omr * ecj) / nrm);
          lloss += wc * (1.f - dt);
          lw += wc;
        }
      }
    }
  } else if (m >= 2 && h == 0){
    // correctness-only solo fallback (never taken on this dataset)
    int* mem = (int*)tile;                        // 31040 ints >= B_
    if (tid == 0) B0_sh = 0;
    __syncthreads();
    for (int i = tid; i < B_; i += NT)
      if (labels[i] == c){ int p = atomicAdd(&B0_sh, 1); mem[p] = i; }
    __syncthreads();
    const int P = m * (m - 1) / 2;
    const int k0 = (P - 1) >> 1;
    const float wc = (float)m;
    const float* cc = cent + (size_t)c * D_;
    const float cno = 1.f / fmaxf(sqrtf(dotg(cc, cc)), 1e-12f);
    for (int p = tid; p < P; p += NT){
      int a, b; decode_pair(p, m, &a, &b);
      float pdp = 1.f - clamp1(S_pair_g(feat, mem[a], mem[b]));
      int lt = 0, eq = 0;
      for (int q = 0; q < P; ++q){
        int a2, b2; decode_pair(q, m, &a2, &b2);
        float pdq = 1.f - clamp1(S_pair_g(feat, mem[a2], mem[b2]));
        lt += (pdq < pdp); eq += (pdq == pdp);
      }
      if (lt <= k0 && k0 < lt + eq) thr_sh = pdp;
    }
    __syncthreads();
    const float thr = thr_sh;
    for (int p = tid; p < P; p += NT){
      int a, b; decode_pair(p, m, &a, &b);
      int ga = mem[a], gb = mem[b];
      float S = S_pair_g(feat, ga, gb);
      float pd = 1.f - clamp1(S);
      if (pd > thr){
        if (ga > gb){ int t2 = ga; ga = gb; gb = t2; }
        const float* ra = feat + (size_t)ga * D_;
        const float* rb = feat + (size_t)gb * D_;
        float eci = dotg(ra, cc) / fmaxf(sqrtf(dotg(ra, ra)), 1e-12f) * cno;
        float ecj = dotg(rb, cc) / fmaxf(sqrtf(dotg(rb, rb)), 1e-12f) * cno;
        float r = rand_ij((unsigned)ga * (unsigned)B_ + (unsigned)gb);
        float omr = 1.f - r;
        float n2 = r * r + omr * omr + 2.f * r * omr * S;
        float nrm = fmaxf(sqrtf(fmaxf(n2, 0.f)), 1e-12f);
        float dt = clamp1((r * eci + omr * ecj) / nrm);
        lloss += wc * (1.f - dt);
        lw += wc;
      }
    }
  }

  // ---- tail: block reduce, device accumulate, last of 256 blocks finalizes ----
  lloss = wave_red(lloss); lw = wave_red(lw);
  if (lane == 0){ redbuf[wid] = lloss; redbuf[NW + wid] = lw; }
  __syncthreads();
  if (tid == 0){
    float tl = 0.f, tw = 0.f;
#pragma unroll
    for (int i = 0; i < NW; ++i){ tl += redbuf[i]; tw += redbuf[NW + i]; }
    if (tl != 0.f || tw != 0.f){
      atomicAdd(&acc2[0], tl);
      atomicAdd(&acc2[1], tw);
    }
    __threadfence();
    int old = atomicAdd(done, 1);
    if (old == NBLK - 1){
      float l = atomicAdd(&acc2[0], 0.f);
      float w = atomicAdd(&acc2[1], 0.f);
      out[0] = (w > 0.f) ? (l / w) : 0.f;
    }
  }
}

extern "C" void kernel_launch(void* const* d_in, const int* in_sizes, int n_in,
                              void* d_out, int out_size, void* d_ws, size_t ws_size,
                              hipStream_t stream)
{
  const float* feat   = (const float*)d_in[0];
  const float* cent   = (const float*)d_in[1];
  const int*   labels = (const int*)d_in[2];
  // d_in[3] = cam_ids: unused by the reference computation.

  char* ws = (char*)d_ws;
  size_t avail = (ws_size > (size_t)SRAW_OFF) ? ws_size - SRAW_OFF : 0;
  long long zcap = (long long)((avail < (size_t)Z_CAP) ? avail : (size_t)Z_CAP);

  hipMemsetAsync(ws, 0, (size_t)SRAW_OFF + (size_t)zcap, stream);
  k_all<<<NBLK, NT, 0, stream>>>(feat, cent, labels, ws, (float*)d_out, zcap);
}

// Round 12
// 133.075 us; speedup vs baseline: 2.0399x; 1.3035x over previous
//
#include <hip/hip_runtime.h>

#define B_ 4096
#define C_ 128
#define D_ 768
#define NT 512
#define NW (NT/64)
#define M_MAX 96
#define P_MAX (M_MAX*(M_MAX-1)/2)   // 4560
#define CK 128
#define NCH (D_/CK)                 // 6
#define SROW 132                    // 2-way-only LDS aliasing for row-stride reads
#define RC 127                      // row code meaning "cvec"
#define NIDX_MAX (P_MAX + 2*M_MAX + 1)      // 4753
#define PPT ((NIDX_MAX + NT - 1)/NT)        // 10
#define MAGIC_U 0x5EEDF00Du

__device__ __forceinline__ float wave_red(float v){
#pragma unroll
  for (int o = 32; o > 0; o >>= 1) v += __shfl_down(v, o, 64);
  return v;
}
__device__ __forceinline__ float wave_min(float v){
#pragma unroll
  for (int o = 32; o > 0; o >>= 1) v = fminf(v, __shfl_down(v, o, 64));
  return v;
}
__device__ __forceinline__ float wave_max(float v){
#pragma unroll
  for (int o = 32; o > 0; o >>= 1) v = fmaxf(v, __shfl_down(v, o, 64));
  return v;
}
__device__ __forceinline__ float clamp1(float x){ return fminf(fmaxf(x, -1.f), 1.f); }
__device__ __forceinline__ unsigned rotl32(unsigned x, int r){ return (x << r) | (x >> (32 - r)); }
__device__ __forceinline__ float dot4(float4 a, float4 b){
  return fmaf(a.x, b.x, fmaf(a.y, b.y, fmaf(a.z, b.z, a.w * b.w)));
}

// jax.random.uniform(jax.random.key(1),(B,B)) element n: Threefry-2x32 key (0,1),
// counters split in halves. Bit-exact (verified rounds 1-11: absmax 0.0).
__device__ float rand_ij(unsigned n){
  const unsigned half = (unsigned)B_ * (unsigned)B_ / 2u;
  unsigned c0, c1; bool hi;
  if (n < half){ c0 = n; c1 = n + half; hi = false; }
  else         { c0 = n - half; c1 = n; hi = true; }
  const unsigned K0 = 0u, K1 = 1u, K2 = 0x1BD11BDBu;
  unsigned x0 = c0 + K0, x1 = c1 + K1;
#define TFR(r) { x0 += x1; x1 = rotl32(x1, (r)); x1 ^= x0; }
  TFR(13) TFR(15) TFR(26) TFR(6)  x0 += K1; x1 += K2 + 1u;
  TFR(17) TFR(29) TFR(16) TFR(24) x0 += K2; x1 += K0 + 2u;
  TFR(13) TFR(15) TFR(26) TFR(6)  x0 += K0; x1 += K1 + 3u;
  TFR(17) TFR(29) TFR(16) TFR(24) x0 += K1; x1 += K2 + 4u;
  TFR(13) TFR(15) TFR(26) TFR(6)  x0 += K2; x1 += K0 + 5u;
#undef TFR
  unsigned bits = hi ? x1 : x0;
  return __uint_as_float((bits >> 9) | 0x3F800000u) - 1.0f;
}

// p -> (a,b), a<b<m, row-major upper-tri. before(a) = a*(2m-1-a)/2.
__device__ __forceinline__ void decode_pair(int p, int m, int* a_, int* b_){
  float fm = (float)(2*m - 1);
  int a = (int)((fm - sqrtf(fm*fm - 8.0f*(float)p)) * 0.5f);
  a = max(0, min(a, m - 2));
  while (a > 0 && (a*(2*m - 1 - a))/2 > p) --a;
  while (((a + 1)*(2*m - 2 - a))/2 <= p) ++a;
  *a_ = a;
  *b_ = a + 1 + (p - (a*(2*m - 1 - a))/2);
}

// ---- slow-path helpers (unreachable: all classes m<=96; insurance only) ----
__device__ float dotg(const float* x, const float* y){
  float s = 0.f;
  for (int k = 0; k < D_; ++k) s = fmaf(x[k], y[k], s);
  return s;
}
__device__ float S_pair_g(const float* feat, int ga, int gb){
  const float* ra = feat + (size_t)ga * D_;
  const float* rb = feat + (size_t)gb * D_;
  float d = dotg(ra, rb);
  float na = 1.f / fmaxf(sqrtf(dotg(ra, ra)), 1e-12f);
  float nb = 1.f / fmaxf(sqrtf(dotg(rb, rb)), 1e-12f);
  return d * na * nb;
}

// ==== single kernel, single graph node: one block per class (R7 body) ====
__global__ __launch_bounds__(NT) void k_all(
    const float* __restrict__ feat, const float* __restrict__ cent,
    const int* __restrict__ labels,
    float* __restrict__ lossv, float* __restrict__ wv,
    unsigned* __restrict__ flags, float* __restrict__ out)
{
  const int c = blockIdx.x;
  const int tid = threadIdx.x;
  const int wid = tid >> 6, lane = tid & 63;

  __shared__ int   gid_s[M_MAX];
  __shared__ int   mcount;
  __shared__ __align__(16) float tile[M_MAX * SROW];   // 50688 B
  __shared__ __align__(16) float cvec[CK];
  __shared__ __align__(16) float Sl[P_MAX];
  __shared__ __align__(16) float Pd[P_MAX];
  __shared__ unsigned short fidx_s[P_MAX];
  __shared__ float selfs[M_MAX];
  __shared__ float ecs[M_MAX];
  __shared__ float cn_sh;
  __shared__ int   wcnt[NW * 64];
  __shared__ float mnb[NW], mxb[NW];
  __shared__ float lo_sh, sF_sh;
  __shared__ int   B0_sh, ex_sh, B1_sh;
  __shared__ float thr_sh;
  __shared__ float redbuf[16];
  __shared__ int   okc;

  // ---- phase A: collect members of class c (order-independent math) ----
  if (tid == 0) mcount = 0;
  __syncthreads();
  for (int i = tid; i < B_; i += NT){
    if (labels[i] == c){
      int p = atomicAdd(&mcount, 1);
      if (p < M_MAX) gid_s[p] = i;
    }
  }
  __syncthreads();
  const int m = mcount;

  float lloss = 0.f, lw = 0.f;

  if (m >= 2 && m <= M_MAX){
    const int P = m * (m - 1) / 2;
    const int k0 = (P - 1) >> 1;
    const float wc = (float)m;

    // slot setup: one index per dot product
    const int NIDX = P + 2*m + 1;
    int   nsl = 0;
    int   meta[PPT];      // (idx<<14) | (ra<<7) | rb   (RC=127 means cvec)
    float acc[PPT];
#pragma unroll
    for (int t = 0; t < PPT; ++t){ acc[t] = 0.f; meta[t] = 0; }
    for (int idx = tid; idx < NIDX; idx += NT){
      int ra, rb;
      if (idx < P){ decode_pair(idx, m, &ra, &rb); }
      else if (idx < P + m){ ra = rb = idx - P; }
      else if (idx < P + 2*m){ ra = idx - P - m; rb = RC; }
      else { ra = RC; rb = RC; }
      meta[nsl++] = (idx << 14) | (ra << 7) | rb;
    }

    // ---- phase B: chunked staging + thread-per-dot Gram ----
    for (int ch = 0; ch < NCH; ++ch){
      const int d0 = ch * CK;
      __syncthreads();
      for (int e = tid; e < m * (CK/4); e += NT){
        int r = e >> 5, j = e & 31;
        ((float4*)&tile[r * SROW])[j] =
            ((const float4*)(feat + (size_t)gid_s[r] * D_ + d0))[j];
      }
      if (tid < CK/4)
        ((float4*)cvec)[tid] = ((const float4*)(cent + (size_t)c * D_ + d0))[tid];
      __syncthreads();
#pragma unroll
      for (int t = 0; t < PPT; ++t){
        if (t < nsl){
          const int mt = meta[t];
          const int ra = (mt >> 7) & 127, rb = mt & 127;
          const float4* A = (ra == RC) ? (const float4*)cvec : (const float4*)&tile[ra * SROW];
          const float4* Bp = (rb == RC) ? (const float4*)cvec : (const float4*)&tile[rb * SROW];
          float s = 0.f;
#pragma unroll 8
          for (int j = 0; j < CK/4; ++j) s += dot4(A[j], Bp[j]);
          acc[t] += s;
        }
      }
    }
    __syncthreads();

    // combine: owner-writes raw dots
#pragma unroll
    for (int t = 0; t < PPT; ++t){
      if (t < nsl){
        const int p2 = meta[t] >> 14;
        const float v = acc[t];
        if (p2 < P) Sl[p2] = v;
        else if (p2 < P + m) selfs[p2 - P] = v;
        else if (p2 < P + 2*m) ecs[p2 - P - m] = v;
        else cn_sh = v;
      }
    }
    __syncthreads();
    if (tid < m){
      float rn  = 1.f / fmaxf(sqrtf(selfs[tid]), 1e-12f);
      float cno = 1.f / fmaxf(sqrtf(cn_sh), 1e-12f);
      selfs[tid] = rn;
      ecs[tid] = ecs[tid] * rn * cno;
    }
    __syncthreads();

    // ---- phase C: normalize pairs, compute pd, track min/max ----
    float pmn = 1e30f, pmx = -1e30f;
    for (int p = tid; p < P; p += NT){
      int a, b; decode_pair(p, m, &a, &b);
      float S = Sl[p] * selfs[a] * selfs[b];
      float pd = 1.f - clamp1(S);
      Sl[p] = S; Pd[p] = pd;
      pmn = fminf(pmn, pd); pmx = fmaxf(pmx, pd);
    }
    pmn = wave_min(pmn); pmx = wave_max(pmx);
    if (lane == 0){ mnb[wid] = pmn; mxb[wid] = pmx; }
    __syncthreads();
    if (tid == 0){
      float mn = mnb[0], mx = mxb[0];
#pragma unroll
      for (int i = 1; i < NW; ++i){ mn = fminf(mn, mnb[i]); mx = fmaxf(mx, mxb[i]); }
      lo_sh = mn;
      sF_sh = 4096.f / fmaxf(mx - mn, 1e-20f);
    }
    __syncthreads();
    const float lo = lo_sh, sF = sF_sh;

    // ---- phase D: two-level ballot rank-select (4096 fine buckets) ----
    const int nch = (P + NT - 1) / NT;
    int cl = 0;
    for (int t = 0; t < nch; ++t){
      int p = tid + t * NT;
      int bkt = -1;
      if (p < P){
        int f = (int)((Pd[p] - lo) * sF);
        f = max(0, min(4095, f));
        fidx_s[p] = (unsigned short)f;
        bkt = f >> 6;
      }
#pragma unroll
      for (int k = 0; k < 64; ++k){
        unsigned long long msk = __ballot(bkt == k);
        if (lane == k) cl += __popcll(msk);
      }
    }
    wcnt[wid*64 + lane] = cl;
    __syncthreads();
    if (tid < 64){
      int tot = 0;
#pragma unroll
      for (int w = 0; w < NW; ++w) tot += wcnt[w*64 + tid];
      int inc = tot;
#pragma unroll
      for (int o = 1; o < 64; o <<= 1){
        int v = __shfl_up(inc, o, 64);
        if (tid >= o) inc += v;
      }
      int excl = inc - tot;
      if (excl <= k0 && k0 < inc){ B0_sh = tid; ex_sh = excl; }
    }
    __syncthreads();
    const int Bsel0 = B0_sh;
    const int kt = k0 - ex_sh;
    cl = 0;
    for (int t = 0; t < nch; ++t){
      int p = tid + t * NT;
      int bkt = -1;
      if (p < P){
        int f = fidx_s[p];
        if ((f >> 6) == Bsel0) bkt = f & 63;
      }
#pragma unroll
      for (int k = 0; k < 64; ++k){
        unsigned long long msk = __ballot(bkt == k);
        if (lane == k) cl += __popcll(msk);
      }
    }
    wcnt[wid*64 + lane] = cl;
    __syncthreads();
    if (tid < 64){
      int tot = 0;
#pragma unroll
      for (int w = 0; w < NW; ++w) tot += wcnt[w*64 + tid];
      int inc = tot;
#pragma unroll
      for (int o = 1; o < 64; o <<= 1){
        int v = __shfl_up(inc, o, 64);
        if (tid >= o) inc += v;
      }
      int excl = inc - tot;
      if (excl <= kt && kt < inc) B1_sh = tid;
    }
    __syncthreads();
    const int fsel = (Bsel0 << 6) | B1_sh;

    // exact recount for the ~1-2 candidates in the fine bucket (bit-exact thr)
    {
      const float4* Pd4 = (const float4*)Pd;
      const int nq4 = P >> 2;
      for (int p = tid; p < P; p += NT){
        if (fidx_s[p] == (unsigned short)fsel){
          const float pdp = Pd[p];
          int lt = 0, eq = 0;
#pragma unroll 4
          for (int q4 = 0; q4 < nq4; ++q4){
            float4 v = Pd4[q4];
            lt += (v.x < pdp) + (v.y < pdp) + (v.z < pdp) + (v.w < pdp);
            eq += (v.x == pdp) + (v.y == pdp) + (v.z == pdp) + (v.w == pdp);
          }
          for (int q = nq4 << 2; q < P; ++q){
            float pdq = Pd[q];
            lt += (pdq < pdp); eq += (pdq == pdp);
          }
          if (lt <= k0 && k0 < lt + eq) thr_sh = pdp;
        }
      }
    }
    __syncthreads();
    const float thr = thr_sh;

    // ---- phase E: loss over selected pairs ----
    for (int p = tid; p < P; p += NT){
      float pd = Pd[p];
      if (pd > thr){
        float S = Sl[p];
        int a, b; decode_pair(p, m, &a, &b);
        int ga = gid_s[a], gb = gid_s[b];
        float ea = ecs[a], eb = ecs[b];
        int i, j; float eci, ecj;
        if (ga < gb){ i = ga; j = gb; eci = ea; ecj = eb; }
        else        { i = gb; j = ga; eci = eb; ecj = ea; }
        float r = rand_ij((unsigned)i * (unsigned)B_ + (unsigned)j);
        float omr = 1.f - r;
        float n2 = r * r + omr * omr + 2.f * r * omr * S;    // raw (unclipped) S
        float nrm = fmaxf(sqrtf(fmaxf(n2, 0.f)), 1e-12f);
        float dt = clamp1((r * eci + omr * ecj) / nrm);
        lloss += wc * (1.f - dt);
        lw += wc;
      }
    }
  } else if (m > M_MAX){
    // correctness-only fallback (impossible here: all m<=96, verified R1-R11)
    int* mem = (int*)Sl;
    if (tid == 0) B0_sh = 0;
    __syncthreads();
    for (int i = tid; i < B_; i += NT)
      if (labels[i] == c){ int p = atomicAdd(&B0_sh, 1); mem[p] = i; }
    __syncthreads();
    const int P = m * (m - 1) / 2;
    const int k0 = (P - 1) >> 1;
    const float wc = (float)m;
    const float* cc = cent + (size_t)c * D_;
    const float cno = 1.f / fmaxf(sqrtf(dotg(cc, cc)), 1e-12f);
    for (int p = tid; p < P; p += NT){
      int a, b; decode_pair(p, m, &a, &b);
      float pdp = 1.f - clamp1(S_pair_g(feat, mem[a], mem[b]));
      int lt = 0, eq = 0;
      for (int q = 0; q < P; ++q){
        int a2, b2; decode_pair(q, m, &a2, &b2);
        float pdq = 1.f - clamp1(S_pair_g(feat, mem[a2], mem[b2]));
        lt += (pdq < pdp); eq += (pdq == pdp);
      }
      if (lt <= k0 && k0 < lt + eq) thr_sh = pdp;
    }
    __syncthreads();
    const float thr = thr_sh;
    for (int p = tid; p < P; p += NT){
      int a, b; decode_pair(p, m, &a, &b);
      int ga = mem[a], gb = mem[b];
      float S = S_pair_g(feat, ga, gb);
      float pd = 1.f - clamp1(S);
      if (pd > thr){
        if (ga > gb){ int t2 = ga; ga = gb; gb = t2; }
        const float* ra = feat + (size_t)ga * D_;
        const float* rb = feat + (size_t)gb * D_;
        float eci = dotg(ra, cc) / fmaxf(sqrtf(dotg(ra, ra)), 1e-12f) * cno;
        float ecj = dotg(rb, cc) / fmaxf(sqrtf(dotg(rb, rb)), 1e-12f) * cno;
        float r = rand_ij((unsigned)ga * (unsigned)B_ + (unsigned)gb);
        float omr = 1.f - r;
        float n2 = r * r + omr * omr + 2.f * r * omr * S;
        float nrm = fmaxf(sqrtf(fmaxf(n2, 0.f)), 1e-12f);
        float dt = clamp1((r * eci + omr * ecj) / nrm);
        lloss += wc * (1.f - dt);
        lw += wc;
      }
    }
  }
  // m < 2: contributes zeros

  // ---- phase F: publish per-class result, then init-agnostic completion ----
  lloss = wave_red(lloss); lw = wave_red(lw);
  if (lane == 0){ redbuf[wid] = lloss; redbuf[8 + wid] = lw; }
  __syncthreads();
  if (tid == 0){
    float tl = 0.f, tw = 0.f;
#pragma unroll
    for (int i = 0; i < NW; ++i){ tl += redbuf[i]; tw += redbuf[8 + i]; }
    lossv[c] = tl;               // plain stores: any initial ws content overwritten
    wv[c] = tw;
    __threadfence();             // release before publishing
    atomicExch(&flags[c], MAGIC_U);
  }
  if (tid == 0) okc = 0;
  __syncthreads();
  // every block scans all flags with device-scope reads; any block seeing all
  // 128 == MAGIC finalizes (idempotent: all finalizers write the same value)
  if (tid < C_){
    unsigned v = atomicAdd(&flags[tid], 0u);
    if (v == MAGIC_U) atomicAdd(&okc, 1);
  }
  __syncthreads();
  if (okc == C_){
    float lv = 0.f, wvv = 0.f;
    if (tid < C_){
      lv  = atomicAdd(&lossv[tid], 0.f);   // device-scope coherent reads
      wvv = atomicAdd(&wv[tid], 0.f);
    }
    lv = wave_red(lv); wvv = wave_red(wvv);
    if (lane == 0){ redbuf[wid] = lv; redbuf[8 + wid] = wvv; }
    __syncthreads();
    if (tid == 0){
      float l = redbuf[0] + redbuf[1];     // tid<128 spans waves 0,1
      float w = redbuf[8] + redbuf[9];
      out[0] = (w > 0.f) ? (l / w) : 0.f;
    }
  }
}

extern "C" void kernel_launch(void* const* d_in, const int* in_sizes, int n_in,
                              void* d_out, int out_size, void* d_ws, size_t ws_size,
                              hipStream_t stream)
{
  const float* feat   = (const float*)d_in[0];
  const float* cent   = (const float*)d_in[1];
  const int*   labels = (const int*)d_in[2];
  // d_in[3] = cam_ids: unused by the reference computation.

  char* ws = (char*)d_ws;
  float*    lossv = (float*)(ws + 0);      // 128 floats
  float*    wvv   = (float*)(ws + 512);    // 128 floats
  unsigned* flags = (unsigned*)(ws + 1024);// 128 uints

  // single graph node: no memset needed (kernel is init-agnostic on ws)
  k_all<<<C_, NT, 0, stream>>>(feat, cent, labels, lossv, wvv, flags, (float*)d_out);
}

// Round 13
// 132.442 us; speedup vs baseline: 2.0496x; 1.0048x over previous
//
#include <hip/hip_runtime.h>

#define B_ 4096
#define C_ 128
#define D_ 768
#define NT 512
#define NW (NT/64)
#define M_MAX 96
#define P_MAX (M_MAX*(M_MAX-1)/2)   // 4560
#define CK 128
#define NCH (D_/CK)                 // 6
#define SROW 132                    // floats; 2-way-only LDS aliasing
#define TILE_F (M_MAX*SROW)         // 12672 floats per buffer
#define RC 127                      // row code meaning "cvec"
#define NIDX_MAX (P_MAX + 2*M_MAX + 1)      // 4753
#define PPT ((NIDX_MAX + NT - 1)/NT)        // 10
#define SPT ((M_MAX*(CK/4) + NT - 1)/NT)    // 6 staging float4s per thread
#define MAGIC_U 0x5EEDF00Du

__device__ __forceinline__ float wave_red(float v){
#pragma unroll
  for (int o = 32; o > 0; o >>= 1) v += __shfl_down(v, o, 64);
  return v;
}
__device__ __forceinline__ float wave_min(float v){
#pragma unroll
  for (int o = 32; o > 0; o >>= 1) v = fminf(v, __shfl_down(v, o, 64));
  return v;
}
__device__ __forceinline__ float wave_max(float v){
#pragma unroll
  for (int o = 32; o > 0; o >>= 1) v = fmaxf(v, __shfl_down(v, o, 64));
  return v;
}
__device__ __forceinline__ float clamp1(float x){ return fminf(fmaxf(x, -1.f), 1.f); }
__device__ __forceinline__ unsigned rotl32(unsigned x, int r){ return (x << r) | (x >> (32 - r)); }
__device__ __forceinline__ float dot4(float4 a, float4 b){
  return fmaf(a.x, b.x, fmaf(a.y, b.y, fmaf(a.z, b.z, a.w * b.w)));
}

// jax.random.uniform(jax.random.key(1),(B,B)) element n: Threefry-2x32 key (0,1),
// counters split in halves. Bit-exact (verified rounds 1-12: absmax 0.0).
__device__ float rand_ij(unsigned n){
  const unsigned half = (unsigned)B_ * (unsigned)B_ / 2u;
  unsigned c0, c1; bool hi;
  if (n < half){ c0 = n; c1 = n + half; hi = false; }
  else         { c0 = n - half; c1 = n; hi = true; }
  const unsigned K0 = 0u, K1 = 1u, K2 = 0x1BD11BDBu;
  unsigned x0 = c0 + K0, x1 = c1 + K1;
#define TFR(r) { x0 += x1; x1 = rotl32(x1, (r)); x1 ^= x0; }
  TFR(13) TFR(15) TFR(26) TFR(6)  x0 += K1; x1 += K2 + 1u;
  TFR(17) TFR(29) TFR(16) TFR(24) x0 += K2; x1 += K0 + 2u;
  TFR(13) TFR(15) TFR(26) TFR(6)  x0 += K0; x1 += K1 + 3u;
  TFR(17) TFR(29) TFR(16) TFR(24) x0 += K1; x1 += K2 + 4u;
  TFR(13) TFR(15) TFR(26) TFR(6)  x0 += K2; x1 += K0 + 5u;
#undef TFR
  unsigned bits = hi ? x1 : x0;
  return __uint_as_float((bits >> 9) | 0x3F800000u) - 1.0f;
}

// p -> (a,b), a<b<m, row-major upper-tri. before(a) = a*(2m-1-a)/2.
__device__ __forceinline__ void decode_pair(int p, int m, int* a_, int* b_){
  float fm = (float)(2*m - 1);
  int a = (int)((fm - sqrtf(fm*fm - 8.0f*(float)p)) * 0.5f);
  a = max(0, min(a, m - 2));
  while (a > 0 && (a*(2*m - 1 - a))/2 > p) --a;
  while (((a + 1)*(2*m - 2 - a))/2 <= p) ++a;
  *a_ = a;
  *b_ = a + 1 + (p - (a*(2*m - 1 - a))/2);
}

// ---- slow-path helpers (unreachable: all classes m<=96; insurance only) ----
__device__ float dotg(const float* x, const float* y){
  float s = 0.f;
  for (int k = 0; k < D_; ++k) s = fmaf(x[k], y[k], s);
  return s;
}
__device__ float S_pair_g(const float* feat, int ga, int gb){
  const float* ra = feat + (size_t)ga * D_;
  const float* rb = feat + (size_t)gb * D_;
  float d = dotg(ra, rb);
  float na = 1.f / fmaxf(sqrtf(dotg(ra, ra)), 1e-12f);
  float nb = 1.f / fmaxf(sqrtf(dotg(rb, rb)), 1e-12f);
  return d * na * nb;
}

// ==== single kernel, single graph node, software-pipelined staging ====
__global__ __launch_bounds__(NT) void k_all(
    const float* __restrict__ feat, const float* __restrict__ cent,
    const int* __restrict__ labels,
    float* __restrict__ lossv, float* __restrict__ wv,
    unsigned* __restrict__ flags, float* __restrict__ out)
{
  const int c = blockIdx.x;
  const int tid = threadIdx.x;
  const int wid = tid >> 6, lane = tid & 63;

  __shared__ int   gid_s[M_MAX];
  __shared__ int   mcount;
  __shared__ __align__(16) float tile[2 * TILE_F];     // 101376 B, double-buffered
  __shared__ __align__(16) float cvec[2][CK];
  // select arrays overlay tile buffer 0 (only used after the last gram, which
  // reads buffer 1; 2*P_MAX + P_MAX/2 floats = 10260 <= TILE_F = 12672)
  float*          Sl     = tile;
  float*          Pd     = tile + P_MAX;
  unsigned short* fidx_s = (unsigned short*)(tile + 2 * P_MAX);
  __shared__ float selfs[M_MAX];
  __shared__ float ecs[M_MAX];
  __shared__ float cn_sh;
  __shared__ int   wcnt[NW * 64];
  __shared__ float mnb[NW], mxb[NW];
  __shared__ float lo_sh, sF_sh;
  __shared__ int   B0_sh, ex_sh, B1_sh;
  __shared__ float thr_sh;
  __shared__ float redbuf[16];
  __shared__ int   okc;

  // ---- phase A: collect members of class c (int4 label loads) ----
  if (tid == 0) mcount = 0;
  __syncthreads();
  {
    const int4* lab4 = (const int4*)labels;
    for (int i = tid; i < B_ / 4; i += NT){
      int4 L = lab4[i];
      int base = i << 2;
      if (L.x == c){ int p = atomicAdd(&mcount, 1); if (p < M_MAX) gid_s[p] = base; }
      if (L.y == c){ int p = atomicAdd(&mcount, 1); if (p < M_MAX) gid_s[p] = base + 1; }
      if (L.z == c){ int p = atomicAdd(&mcount, 1); if (p < M_MAX) gid_s[p] = base + 2; }
      if (L.w == c){ int p = atomicAdd(&mcount, 1); if (p < M_MAX) gid_s[p] = base + 3; }
    }
  }
  __syncthreads();
  const int m = mcount;

  float lloss = 0.f, lw = 0.f;

  if (m >= 2 && m <= M_MAX){
    const int P = m * (m - 1) / 2;
    const int k0 = (P - 1) >> 1;
    const float wc = (float)m;
    const int nst = m * (CK / 4);       // staging float4s per chunk

    // slot setup: one index per dot product
    const int NIDX = P + 2*m + 1;
    int   nsl = 0;
    int   meta[PPT];      // (idx<<14) | (ra<<7) | rb   (RC=127 means cvec)
    float acc[PPT];
#pragma unroll
    for (int t = 0; t < PPT; ++t){ acc[t] = 0.f; meta[t] = 0; }
    for (int idx = tid; idx < NIDX; idx += NT){
      int ra, rb;
      if (idx < P){ decode_pair(idx, m, &ra, &rb); }
      else if (idx < P + m){ ra = rb = idx - P; }
      else if (idx < P + 2*m){ ra = idx - P - m; rb = RC; }
      else { ra = RC; rb = RC; }
      meta[nsl++] = (idx << 14) | (ra << 7) | rb;
    }

    // ---- phase B: double-buffered staging, loads overlap gram compute ----
    float4 pf[SPT];
    float4 cpf;
    // preload + store chunk 0 (the single exposed staging latency)
#pragma unroll
    for (int k = 0; k < SPT; ++k){
      int e = tid + k * NT;
      if (e < nst){
        int r = e >> 5, j = e & 31;
        pf[k] = ((const float4*)(feat + (size_t)gid_s[r] * D_))[j];
      }
    }
    if (tid < CK/4) cpf = ((const float4*)(cent + (size_t)c * D_))[tid];
#pragma unroll
    for (int k = 0; k < SPT; ++k){
      int e = tid + k * NT;
      if (e < nst){
        int r = e >> 5, j = e & 31;
        ((float4*)&tile[r * SROW])[j] = pf[k];
      }
    }
    if (tid < CK/4) ((float4*)cvec[0])[tid] = cpf;
    __syncthreads();

    for (int ch = 0; ch < NCH; ++ch){
      const int cur = ch & 1;
      // issue next chunk's global loads (in flight during gram below)
      if (ch + 1 < NCH){
        const int d0 = (ch + 1) * CK;
#pragma unroll
        for (int k = 0; k < SPT; ++k){
          int e = tid + k * NT;
          if (e < nst){
            int r = e >> 5, j = e & 31;
            pf[k] = ((const float4*)(feat + (size_t)gid_s[r] * D_ + d0))[j];
          }
        }
        if (tid < CK/4) cpf = ((const float4*)(cent + (size_t)c * D_ + d0))[tid];
      }
      // gram on current buffer
      {
        const float* tl = tile + cur * TILE_F;
        const float* cv = cvec[cur];
#pragma unroll
        for (int t = 0; t < PPT; ++t){
          if (t < nsl){
            const int mt = meta[t];
            const int ra = (mt >> 7) & 127, rb = mt & 127;
            const float4* A  = (ra == RC) ? (const float4*)cv : (const float4*)&tl[ra * SROW];
            const float4* Bp = (rb == RC) ? (const float4*)cv : (const float4*)&tl[rb * SROW];
            float s = 0.f;
#pragma unroll 8
            for (int j = 0; j < CK/4; ++j) s += dot4(A[j], Bp[j]);
            acc[t] += s;
          }
        }
      }
      __syncthreads();                 // all gram reads of the other buffer done
      if (ch + 1 < NCH){
        float* tn = tile + (cur ^ 1) * TILE_F;
#pragma unroll
        for (int k = 0; k < SPT; ++k){
          int e = tid + k * NT;
          if (e < nst){
            int r = e >> 5, j = e & 31;
            ((float4*)&tn[r * SROW])[j] = pf[k];
          }
        }
        if (tid < CK/4) ((float4*)cvec[cur ^ 1])[tid] = cpf;
        __syncthreads();
      }
    }

    // combine: owner-writes raw dots (into buffer-0 overlay; gram all done)
#pragma unroll
    for (int t = 0; t < PPT; ++t){
      if (t < nsl){
        const int p2 = meta[t] >> 14;
        const float v = acc[t];
        if (p2 < P) Sl[p2] = v;
        else if (p2 < P + m) selfs[p2 - P] = v;
        else if (p2 < P + 2*m) ecs[p2 - P - m] = v;
        else cn_sh = v;
      }
    }
    __syncthreads();
    if (tid < m){
      float rn  = 1.f / fmaxf(sqrtf(selfs[tid]), 1e-12f);
      float cno = 1.f / fmaxf(sqrtf(cn_sh), 1e-12f);
      selfs[tid] = rn;
      ecs[tid] = ecs[tid] * rn * cno;
    }
    __syncthreads();

    // ---- phase C: normalize pairs, compute pd, track min/max ----
    float pmn = 1e30f, pmx = -1e30f;
    for (int p = tid; p < P; p += NT){
      int a, b; decode_pair(p, m, &a, &b);
      float S = Sl[p] * selfs[a] * selfs[b];
      float pd = 1.f - clamp1(S);
      Sl[p] = S; Pd[p] = pd;
      pmn = fminf(pmn, pd); pmx = fmaxf(pmx, pd);
    }
    pmn = wave_min(pmn); pmx = wave_max(pmx);
    if (lane == 0){ mnb[wid] = pmn; mxb[wid] = pmx; }
    __syncthreads();
    if (tid == 0){
      float mn = mnb[0], mx = mxb[0];
#pragma unroll
      for (int i = 1; i < NW; ++i){ mn = fminf(mn, mnb[i]); mx = fmaxf(mx, mxb[i]); }
      lo_sh = mn;
      sF_sh = 4096.f / fmaxf(mx - mn, 1e-20f);
    }
    __syncthreads();
    const float lo = lo_sh, sF = sF_sh;

    // ---- phase D: two-level ballot rank-select (4096 fine buckets) ----
    const int nch = (P + NT - 1) / NT;
    int cl = 0;
    for (int t = 0; t < nch; ++t){
      int p = tid + t * NT;
      int bkt = -1;
      if (p < P){
        int f = (int)((Pd[p] - lo) * sF);
        f = max(0, min(4095, f));
        fidx_s[p] = (unsigned short)f;
        bkt = f >> 6;
      }
#pragma unroll
      for (int k = 0; k < 64; ++k){
        unsigned long long msk = __ballot(bkt == k);
        if (lane == k) cl += __popcll(msk);
      }
    }
    wcnt[wid*64 + lane] = cl;
    __syncthreads();
    if (tid < 64){
      int tot = 0;
#pragma unroll
      for (int w = 0; w < NW; ++w) tot += wcnt[w*64 + tid];
      int inc = tot;
#pragma unroll
      for (int o = 1; o < 64; o <<= 1){
        int v = __shfl_up(inc, o, 64);
        if (tid >= o) inc += v;
      }
      int excl = inc - tot;
      if (excl <= k0 && k0 < inc){ B0_sh = tid; ex_sh = excl; }
    }
    __syncthreads();
    const int Bsel0 = B0_sh;
    const int kt = k0 - ex_sh;
    cl = 0;
    for (int t = 0; t < nch; ++t){
      int p = tid + t * NT;
      int bkt = -1;
      if (p < P){
        int f = fidx_s[p];
        if ((f >> 6) == Bsel0) bkt = f & 63;
      }
#pragma unroll
      for (int k = 0; k < 64; ++k){
        unsigned long long msk = __ballot(bkt == k);
        if (lane == k) cl += __popcll(msk);
      }
    }
    wcnt[wid*64 + lane] = cl;
    __syncthreads();
    if (tid < 64){
      int tot = 0;
#pragma unroll
      for (int w = 0; w < NW; ++w) tot += wcnt[w*64 + tid];
      int inc = tot;
#pragma unroll
      for (int o = 1; o < 64; o <<= 1){
        int v = __shfl_up(inc, o, 64);
        if (tid >= o) inc += v;
      }
      int excl = inc - tot;
      if (excl <= kt && kt < inc) B1_sh = tid;
    }
    __syncthreads();
    const int fsel = (Bsel0 << 6) | B1_sh;

    // exact recount for the ~1-2 candidates in the fine bucket (bit-exact thr)
    {
      const float4* Pd4 = (const float4*)Pd;
      const int nq4 = P >> 2;
      for (int p = tid; p < P; p += NT){
        if (fidx_s[p] == (unsigned short)fsel){
          const float pdp = Pd[p];
          int lt = 0, eq = 0;
#pragma unroll 4
          for (int q4 = 0; q4 < nq4; ++q4){
            float4 v = Pd4[q4];
            lt += (v.x < pdp) + (v.y < pdp) + (v.z < pdp) + (v.w < pdp);
            eq += (v.x == pdp) + (v.y == pdp) + (v.z == pdp) + (v.w == pdp);
          }
          for (int q = nq4 << 2; q < P; ++q){
            float pdq = Pd[q];
            lt += (pdq < pdp); eq += (pdq == pdp);
          }
          if (lt <= k0 && k0 < lt + eq) thr_sh = pdp;
        }
      }
    }
    __syncthreads();
    const float thr = thr_sh;

    // ---- phase E: loss over selected pairs ----
    for (int p = tid; p < P; p += NT){
      float pd = Pd[p];
      if (pd > thr){
        float S = Sl[p];
        int a, b; decode_pair(p, m, &a, &b);
        int ga = gid_s[a], gb = gid_s[b];
        float ea = ecs[a], eb = ecs[b];
        int i, j; float eci, ecj;
        if (ga < gb){ i = ga; j = gb; eci = ea; ecj = eb; }
        else        { i = gb; j = ga; eci = eb; ecj = ea; }
        float r = rand_ij((unsigned)i * (unsigned)B_ + (unsigned)j);
        float omr = 1.f - r;
        float n2 = r * r + omr * omr + 2.f * r * omr * S;    // raw (unclipped) S
        float nrm = fmaxf(sqrtf(fmaxf(n2, 0.f)), 1e-12f);
        float dt = clamp1((r * eci + omr * ecj) / nrm);
        lloss += wc * (1.f - dt);
        lw += wc;
      }
    }
  } else if (m > M_MAX){
    // correctness-only fallback (impossible here: all m<=96, verified R1-R12)
    int* mem = (int*)Sl;
    if (tid == 0) B0_sh = 0;
    __syncthreads();
    for (int i = tid; i < B_; i += NT)
      if (labels[i] == c){ int p = atomicAdd(&B0_sh, 1); mem[p] = i; }
    __syncthreads();
    const int P = m * (m - 1) / 2;
    const int k0 = (P - 1) >> 1;
    const float wc = (float)m;
    const float* cc = cent + (size_t)c * D_;
    const float cno = 1.f / fmaxf(sqrtf(dotg(cc, cc)), 1e-12f);
    for (int p = tid; p < P; p += NT){
      int a, b; decode_pair(p, m, &a, &b);
      float pdp = 1.f - clamp1(S_pair_g(feat, mem[a], mem[b]));
      int lt = 0, eq = 0;
      for (int q = 0; q < P; ++q){
        int a2, b2; decode_pair(q, m, &a2, &b2);
        float pdq = 1.f - clamp1(S_pair_g(feat, mem[a2], mem[b2]));
        lt += (pdq < pdp); eq += (pdq == pdp);
      }
      if (lt <= k0 && k0 < lt + eq) thr_sh = pdp;
    }
    __syncthreads();
    const float thr = thr_sh;
    for (int p = tid; p < P; p += NT){
      int a, b; decode_pair(p, m, &a, &b);
      int ga = mem[a], gb = mem[b];
      float S = S_pair_g(feat, ga, gb);
      float pd = 1.f - clamp1(S);
      if (pd > thr){
        if (ga > gb){ int t2 = ga; ga = gb; gb = t2; }
        const float* ra = feat + (size_t)ga * D_;
        const float* rb = feat + (size_t)gb * D_;
        float eci = dotg(ra, cc) / fmaxf(sqrtf(dotg(ra, ra)), 1e-12f) * cno;
        float ecj = dotg(rb, cc) / fmaxf(sqrtf(dotg(rb, rb)), 1e-12f) * cno;
        float r = rand_ij((unsigned)ga * (unsigned)B_ + (unsigned)gb);
        float omr = 1.f - r;
        float n2 = r * r + omr * omr + 2.f * r * omr * S;
        float nrm = fmaxf(sqrtf(fmaxf(n2, 0.f)), 1e-12f);
        float dt = clamp1((r * eci + omr * ecj) / nrm);
        lloss += wc * (1.f - dt);
        lw += wc;
      }
    }
  }
  // m < 2: contributes zeros

  // ---- phase F: publish per-class result, init-agnostic completion (R12) ----
  lloss = wave_red(lloss); lw = wave_red(lw);
  if (lane == 0){ redbuf[wid] = lloss; redbuf[8 + wid] = lw; }
  __syncthreads();
  if (tid == 0){
    float tl = 0.f, tw = 0.f;
#pragma unroll
    for (int i = 0; i < NW; ++i){ tl += redbuf[i]; tw += redbuf[8 + i]; }
    lossv[c] = tl;
    wv[c] = tw;
    __threadfence();
    atomicExch(&flags[c], MAGIC_U);
  }
  if (tid == 0) okc = 0;
  __syncthreads();
  if (tid < C_){
    unsigned v = atomicAdd(&flags[tid], 0u);
    if (v == MAGIC_U) atomicAdd(&okc, 1);
  }
  __syncthreads();
  if (okc == C_){
    float lv = 0.f, wvv = 0.f;
    if (tid < C_){
      lv  = atomicAdd(&lossv[tid], 0.f);
      wvv = atomicAdd(&wv[tid], 0.f);
    }
    lv = wave_red(lv); wvv = wave_red(wvv);
    if (lane == 0){ redbuf[wid] = lv; redbuf[8 + wid] = wvv; }
    __syncthreads();
    if (tid == 0){
      float l = redbuf[0] + redbuf[1];
      float w = redbuf[8] + redbuf[9];
      out[0] = (w > 0.f) ? (l / w) : 0.f;
    }
  }
}

extern "C" void kernel_launch(void* const* d_in, const int* in_sizes, int n_in,
                              void* d_out, int out_size, void* d_ws, size_t ws_size,
                              hipStream_t stream)
{
  const float* feat   = (const float*)d_in[0];
  const float* cent   = (const float*)d_in[1];
  const int*   labels = (const int*)d_in[2];
  // d_in[3] = cam_ids: unused by the reference computation.

  char* ws = (char*)d_ws;
  float*    lossv = (float*)(ws + 0);      // 128 floats
  float*    wvv   = (float*)(ws + 512);    // 128 floats
  unsigned* flags = (unsigned*)(ws + 1024);// 128 uints

  // single graph node: no memset needed (kernel is init-agnostic on ws)
  k_all<<<C_, NT, 0, stream>>>(feat, cent, labels, lossv, wvv, flags, (float*)d_out);
}